// Round 9
// baseline (198.805 us; speedup 1.0000x reference)
//
#include <hip/hip_runtime.h>
#include <hip/hip_bf16.h>
#include <cstdint>
#include <cstddef>

// Problem constants
#define NFIELD 10
#define BATCH  16384
#define NIDS   20
#define DEMB   16
#define NFEAT  160   // NFIELD * DEMB
#define NEXP   8
#define NS     64
#define NG     3
#define NT     32

// workspace layout (bytes), all regions 16B-aligned
#define BP_OFF_B  0                                // main B-pack: 34*5*64*8*2 = 174,080
#define BM_OFF_B  (BP_OFF_B + 174080)              // main bias fp32[544] = 2,176
#define BT_OFF_B  (BM_OFF_B + 2176)                // tower B-pack: 3*2*2*64*8*2 = 12,288
#define TB2_OFF_B (BT_OFF_B + 12288)               // tower bias fp32[96] = 384
#define OWF_OFF_B (TB2_OFF_B + 384)                // out w fp32[192] = 768
#define OBF_OFF_B (OWF_OFF_B + 768)                // out b fp32[6]

typedef short bfrag __attribute__((ext_vector_type(8)));  // 8 bf16 (4 VGPRs)
typedef float f32x4 __attribute__((ext_vector_type(4)));

__device__ __forceinline__ float bflo(uint32_t u) {
    union { uint32_t u; float f; } c; c.u = u << 16; return c.f;
}
__device__ __forceinline__ float bfhi(uint32_t u) {
    union { uint32_t u; float f; } c; c.u = u & 0xffff0000u; return c.f;
}
__device__ __forceinline__ float bf1(uint16_t v) {
    union { uint32_t u; float f; } c; c.u = ((uint32_t)v) << 16; return c.f;
}
__device__ __forceinline__ uint16_t f2bf(float f) {
    union { float f; uint32_t u; } c; c.f = f;
    uint32_t r = c.u + 0x7fffu + ((c.u >> 16) & 1u);  // RTNE
    return (uint16_t)(r >> 16);
}
__device__ __forceinline__ float ldw(const void* p, int i, bool bf) {
    return bf ? bf1(((const uint16_t*)p)[i]) : ((const float*)p)[i];
}
__device__ __forceinline__ uint16_t ldb16(const void* p, int i, bool bf) {
    return bf ? ((const uint16_t*)p)[i] : f2bf(((const float*)p)[i]);
}
// per-block emb-dtype sniff (thread 0 must call; result via shared)
__device__ __forceinline__ int sniff_bf(const uint32_t* emb_w) {
    int n_bf = 0;
    #pragma unroll
    for (int t = 0; t < 16; ++t) {
        uint32_t wv = emb_w[(size_t)t * 500000];   // <= 30 MB, in-bounds both ways
        uint32_t v = (wv >> 8) & 0x7Fu;
        n_bf += (v >= 0x3Bu && v <= 0x3Fu);
    }
    return n_bf >= 8;
}

// ---------------------------------------------------------------------------
// Kernel P: pack weights (either dtype) into MFMA B-frag bf16 + fp32 biases.
// Main GEMM Wc[k=160][n=544]: n<512 -> expert_w[n>>6][k][n&63];
//   512<=n<536 -> gate_w[(n-512)>>3][k][(n-512)&7]; else 0.
// Frag: [(nt*5+ks)*64+lane]*8+j, element = Wc[ks*32+(lane>>4)*8+j][nt*16+(lane&15)]
// ---------------------------------------------------------------------------
__global__ __launch_bounds__(256) void pack_weights(
    const uint32_t* __restrict__ emb_w,
    const void* __restrict__ ew, const void* __restrict__ eb,
    const void* __restrict__ gw, const void* __restrict__ gb,
    const void* __restrict__ tw, const void* __restrict__ tb,
    const void* __restrict__ ow, const void* __restrict__ ob,
    uint16_t* __restrict__ bp, float* __restrict__ bm,
    uint16_t* __restrict__ bt, float* __restrict__ tb2,
    float* __restrict__ owf, float* __restrict__ obf)
{
    __shared__ int sbf;
    if (threadIdx.x == 0) sbf = sniff_bf(emb_w);
    __syncthreads();
    const bool bf = sbf != 0;

    int i = blockIdx.x * 256 + threadIdx.x;
    if (i < 10880) {                       // main B-pack: 34 tiles * 5 ksteps * 64 lanes
        int nt = i / 320, rem = i % 320;
        int ks = rem / 64, l = rem % 64;
        int n  = nt * 16 + (l & 15);
        int kb = ks * 32 + ((l >> 4) * 8);
        uint16_t v[8];
        #pragma unroll
        for (int j = 0; j < 8; ++j) {
            int k = kb + j;
            uint16_t x;
            if (n < 512)      x = ldb16(ew, (n >> 6) * 10240 + k * 64 + (n & 63), bf);
            else if (n < 536) x = ldb16(gw, ((n - 512) >> 3) * 1280 + k * 8 + ((n - 512) & 7), bf);
            else              x = 0;
            v[j] = x;
        }
        uint4 o;
        o.x = (uint32_t)v[0] | ((uint32_t)v[1] << 16);
        o.y = (uint32_t)v[2] | ((uint32_t)v[3] << 16);
        o.z = (uint32_t)v[4] | ((uint32_t)v[5] << 16);
        o.w = (uint32_t)v[6] | ((uint32_t)v[7] << 16);
        ((uint4*)bp)[i] = o;
    } else if (i < 11648) {                // tower B-pack: 3g * 2nt * 2ks * 64 lanes
        int it = i - 10880;
        int g = it / 256, rem = it % 256;
        int ntile = rem / 128, ks = (rem / 64) & 1, l = rem % 64;
        int t  = ntile * 16 + (l & 15);
        int sb = ks * 32 + ((l >> 4) * 8);
        uint16_t v[8];
        #pragma unroll
        for (int j = 0; j < 8; ++j)
            v[j] = ldb16(tw, g * 2048 + (sb + j) * 32 + t, bf);
        uint4 o;
        o.x = (uint32_t)v[0] | ((uint32_t)v[1] << 16);
        o.y = (uint32_t)v[2] | ((uint32_t)v[3] << 16);
        o.z = (uint32_t)v[4] | ((uint32_t)v[5] << 16);
        o.w = (uint32_t)v[6] | ((uint32_t)v[7] << 16);
        ((uint4*)bt)[it] = o;
    } else if (i < 12192) {                // main bias [544]
        int n = i - 11648;
        bm[n] = (n < 512) ? ldw(eb, n, bf) : (n < 536 ? ldw(gb, n - 512, bf) : 0.0f);
    } else if (i < 12288) {                // tower bias [96]
        int n = i - 12192; tb2[n] = ldw(tb, n, bf);
    } else if (i < 12480) {                // out w [192]
        int n = i - 12288; owf[n] = ldw(ow, n, bf);
    } else if (i < 12486) {                // out b [6]
        int n = i - 12480; obf[n] = ldw(ob, n, bf);
    }
}

// ---------------------------------------------------------------------------
// Kernel F: FUSED gather + MFMA MMoE, sample-split software pipeline.
// 32 samples/block, 512 blocks, 320 threads (5 waves).
//   Phase A: all waves gather samples 0-15  (one half-row item per thread)
//   Phase B: waves 0-2 GEMM M-tile 0  ||  waves 3-4 gather samples 16-31
//   Phase C: waves 0-2 GEMM M-tile 1; epilogue (all waves, tid<256 mostly)
// x-scratch lives in mix_lds (dead until mix); tow overlays exp; prob overlays gate.
// ---------------------------------------------------------------------------
__global__ __launch_bounds__(320, 3) void moe_fused(
    const void* __restrict__ ids_raw,
    const void* __restrict__ emb_raw,
    const uint16_t* __restrict__ bp,   // main B-pack
    const float*    __restrict__ bm,   // main bias [544] fp32
    const uint16_t* __restrict__ btw,  // tower B-pack
    const float*    __restrict__ btb,  // tower bias [96] fp32
    const float*    __restrict__ owf,  // out w [192] fp32
    const float*    __restrict__ obf,  // out b [6] fp32
    void* __restrict__ out)
{
    __shared__ uint16_t exp_lds[32][520];   // 33,280 B (tower overlay later)
    __shared__ float    gate_lds[32][33];   //  4,224 B (prob overlay later)
    __shared__ uint16_t mix_lds[32][200];   // 12,800 B (x-scratch first, mix later)
    __shared__ int      sflags;             // total ~50.3 KB -> 3 blocks/CU

    float* tow  = (float*)&exp_lds[0][0];   // [32][100] overlay
    float* prob = &gate_lds[0][0];          // [32][6] overlay
    uint16_t* xs = &mix_lds[0][0];          // x[s][0..159] at stride 200 halves

    const int tid = threadIdx.x;
    const int w = tid >> 6, l = tid & 63;
    const int lm = l & 15, q = l >> 4;
    const int b0 = blockIdx.x * 32;

    // ---- per-block dtype sniff (thread 0) ----
    if (tid == 0) {
        int n_hi = 0;
        #pragma unroll
        for (int t = 0; t < 16; ++t) {
            size_t p = (size_t)t * 100000;  // pair idx <= 1.5M: in-bounds both ways
            n_hi += (((const uint32_t*)ids_raw)[2 * p + 1] != 0);
        }
        sflags = ((n_hi < 2) ? 1 : 0) | (sniff_bf((const uint32_t*)emb_raw) ? 2 : 0);
    }
    __syncthreads();
    const bool i64 = (sflags & 1) != 0;
    const bool bfe = (sflags & 2) != 0;

    // gather of one half-row item: field f, sample s (global b0+s), half h
    auto gather_half = [&](int f, int s, int h) {
        int idv[NIDS];
        if (i64) {
            const int4* p4 = (const int4*)((const long long*)ids_raw +
                                           ((size_t)f * BATCH + (b0 + s)) * NIDS);
            #pragma unroll
            for (int j = 0; j < NIDS / 2; ++j) {
                int4 t4 = p4[j];
                idv[2 * j + 0] = t4.x;
                idv[2 * j + 1] = t4.z;
            }
        } else {
            const int4* p4 = (const int4*)((const int*)ids_raw +
                                           ((size_t)f * BATCH + (b0 + s)) * NIDS);
            #pragma unroll
            for (int j = 0; j < NIDS / 4; ++j) {
                int4 t4 = p4[j];
                idv[4 * j + 0] = t4.x; idv[4 * j + 1] = t4.y;
                idv[4 * j + 2] = t4.z; idv[4 * j + 3] = t4.w;
            }
        }
        float acc[8];
        #pragma unroll
        for (int d = 0; d < 8; ++d) acc[d] = 0.0f;
        if (bfe) {
            #pragma unroll
            for (int ll = 0; ll < NIDS; ++ll) {
                uint4 r = *(const uint4*)((const uint16_t*)emb_raw +
                                          (size_t)idv[ll] * DEMB + h * 8);
                acc[0] += bflo(r.x); acc[1] += bfhi(r.x);
                acc[2] += bflo(r.y); acc[3] += bfhi(r.y);
                acc[4] += bflo(r.z); acc[5] += bfhi(r.z);
                acc[6] += bflo(r.w); acc[7] += bfhi(r.w);
            }
        } else {
            #pragma unroll
            for (int ll = 0; ll < NIDS; ++ll) {
                const float4* p = (const float4*)((const float*)emb_raw +
                                                  (size_t)idv[ll] * DEMB + h * 8);
                float4 r0 = p[0], r1 = p[1];
                acc[0] += r0.x; acc[1] += r0.y; acc[2] += r0.z; acc[3] += r0.w;
                acc[4] += r1.x; acc[5] += r1.y; acc[6] += r1.z; acc[7] += r1.w;
            }
        }
        uint4 o;
        o.x = (uint32_t)f2bf(acc[0]) | ((uint32_t)f2bf(acc[1]) << 16);
        o.y = (uint32_t)f2bf(acc[2]) | ((uint32_t)f2bf(acc[3]) << 16);
        o.z = (uint32_t)f2bf(acc[4]) | ((uint32_t)f2bf(acc[5]) << 16);
        o.w = (uint32_t)f2bf(acc[6]) | ((uint32_t)f2bf(acc[7]) << 16);
        *(uint4*)(xs + (size_t)s * 200 + f * DEMB + h * 8) = o;
    };

    // GEMM over one M-tile (rows mrow..mrow+15) for waves 0-2 (tiles 12/11/11)
    auto gemm_mtile = [&](int mrow) {
        bfrag a[5];
        #pragma unroll
        for (int ks = 0; ks < 5; ++ks)
            a[ks] = *(const bfrag*)(xs + (size_t)(mrow + lm) * 200 + ks * 32 + q * 8);
        int start = (w == 0) ? 0 : (w == 1) ? 12 : 23;
        int cnt   = (w == 0) ? 12 : 11;
        for (int it = 0; it < cnt; ++it) {
            int nt = start + it;
            f32x4 acc = {0.0f, 0.0f, 0.0f, 0.0f};
            const bfrag* bpp = (const bfrag*)bp + (size_t)(nt * 5) * 64 + l;
            #pragma unroll
            for (int ks = 0; ks < 5; ++ks) {
                bfrag b = bpp[ks * 64];
                acc = __builtin_amdgcn_mfma_f32_16x16x32_bf16(a[ks], b, acc, 0, 0, 0);
            }
            int col = nt * 16 + lm;
            float bias = bm[col];
            if (col < 512) {
                #pragma unroll
                for (int r = 0; r < 4; ++r)
                    exp_lds[mrow + q * 4 + r][col] = f2bf(fmaxf(acc[r] + bias, 0.0f));
            } else {
                #pragma unroll
                for (int r = 0; r < 4; ++r)
                    gate_lds[mrow + q * 4 + r][col - 512] = acc[r] + bias;
            }
        }
    };

    // ---- Phase A: all 320 threads gather samples 0-15 (one item each) ----
    {
        int f = tid >> 5, rem = tid & 31;
        gather_half(f, rem >> 1, rem & 1);
    }
    __syncthreads();

    // ---- Phase B: waves 0-2 GEMM M-tile 0 || waves 3-4 gather samples 16-31 ----
    if (w < 3) {
        gemm_mtile(0);
    } else {
        int local = tid - 192;              // 0..127
        #pragma unroll
        for (int c = 0; c < 3; ++c) {
            int sp = c * 128 + local;
            if (sp < 320) {
                int f = sp >> 5, rem = sp & 31;
                gather_half(f, 16 + (rem >> 1), rem & 1);
            }
        }
    }
    __syncthreads();

    // ---- Phase C: waves 0-2 GEMM M-tile 1 ----
    if (w < 3) gemm_mtile(16);
    __syncthreads();

    const int sm = tid >> 3, j = tid & 7;   // 32 samples x 8 threads (tid<256)

    // ---- gate softmax (tid<256, j<3 -> g=j) ----
    if (tid < 256 && j < 3) {
        float* gl = &gate_lds[sm][j * 8];
        float m = gl[0];
        #pragma unroll
        for (int e = 1; e < 8; ++e) m = fmaxf(m, gl[e]);
        float ex[8], s = 0.0f;
        #pragma unroll
        for (int e = 0; e < 8; ++e) { ex[e] = __expf(gl[e] - m); s += ex[e]; }
        float inv = 1.0f / s;
        #pragma unroll
        for (int e = 0; e < 8; ++e) gl[e] = ex[e] * inv;
    }
    __syncthreads();

    // ---- mix[g][s]: tid<256; thread j does s = j*8..j*8+7 for all g ----
    // (overwrites xs region -- x is dead after phase C's A-frag loads)
    if (tid < 256) {
        for (int g = 0; g < NG; ++g) {
            float m8[8];
            #pragma unroll
            for (int i = 0; i < 8; ++i) m8[i] = 0.0f;
            #pragma unroll
            for (int e = 0; e < NEXP; ++e) {
                float gv = gate_lds[sm][g * 8 + e];
                uint4 u = *(const uint4*)&exp_lds[sm][e * 64 + j * 8];
                m8[0] = fmaf(gv, bflo(u.x), m8[0]); m8[1] = fmaf(gv, bfhi(u.x), m8[1]);
                m8[2] = fmaf(gv, bflo(u.y), m8[2]); m8[3] = fmaf(gv, bfhi(u.y), m8[3]);
                m8[4] = fmaf(gv, bflo(u.z), m8[4]); m8[5] = fmaf(gv, bfhi(u.z), m8[5]);
                m8[6] = fmaf(gv, bflo(u.w), m8[6]); m8[7] = fmaf(gv, bfhi(u.w), m8[7]);
            }
            uint4 o;
            o.x = (uint32_t)f2bf(m8[0]) | ((uint32_t)f2bf(m8[1]) << 16);
            o.y = (uint32_t)f2bf(m8[2]) | ((uint32_t)f2bf(m8[3]) << 16);
            o.z = (uint32_t)f2bf(m8[4]) | ((uint32_t)f2bf(m8[5]) << 16);
            o.w = (uint32_t)f2bf(m8[6]) | ((uint32_t)f2bf(m8[7]) << 16);
            *(uint4*)&mix_lds[sm][g * 64 + j * 8] = o;
        }
    }
    __syncthreads();   // exp region dead; tow overlay live

    // ---- tower MFMA: 12 units (3g x 2mt x 2nt), wave w does u = w, w+5, w+10 ----
    for (int u = w; u < 12; u += 5) {
        int g = u >> 2, mt = (u >> 1) & 1, ntile = u & 1;
        f32x4 acc = {0.0f, 0.0f, 0.0f, 0.0f};
        #pragma unroll
        for (int ks = 0; ks < 2; ++ks) {
            bfrag av = *(const bfrag*)&mix_lds[mt * 16 + lm][g * 64 + ks * 32 + q * 8];
            bfrag bv = *(const bfrag*)(btw + (size_t)((((g * 2 + ntile) * 2 + ks) * 64 + l)) * 8);
            acc = __builtin_amdgcn_mfma_f32_16x16x32_bf16(av, bv, acc, 0, 0, 0);
        }
        int t = ntile * 16 + lm;
        float bias = btb[g * 32 + t];
        #pragma unroll
        for (int r = 0; r < 4; ++r)
            tow[(mt * 16 + q * 4 + r) * 100 + g * 32 + t] = fmaxf(acc[r] + bias, 0.0f);
    }
    __syncthreads();

    // ---- out head: tid<256, j<3 -> g=j: 2 logits, softmax, clip ----
    if (tid < 256 && j < 3) {
        int g = j;
        float l0 = obf[2 * g], l1 = obf[2 * g + 1];
        #pragma unroll 8
        for (int t = 0; t < NT; ++t) {
            float tv = tow[sm * 100 + g * 32 + t];
            l0 = fmaf(tv, owf[g * 64 + 2 * t], l0);
            l1 = fmaf(tv, owf[g * 64 + 2 * t + 1], l1);
        }
        float m  = fmaxf(l0, l1);
        float e0 = __expf(l0 - m);
        float e1 = __expf(l1 - m);
        float inv = 1.0f / (e0 + e1);
        float p0 = fminf(fmaxf(e0 * inv, 1e-15f), 1.0f);
        float p1 = fminf(fmaxf(e1 * inv, 1e-15f), 1.0f);
        prob[sm * 6 + 2 * g + 0] = p0;
        prob[sm * 6 + 2 * g + 1] = p1;
    }
    __syncthreads();

    // ---- assemble 10 outputs per sample (tid<256), dtype per sniff ----
    if (tid < 256) {
        float ctr0 = prob[sm * 6 + 0], ctr1 = prob[sm * 6 + 1];
        float cvr0 = prob[sm * 6 + 2], cvr1 = prob[sm * 6 + 3];
        float imp1 = prob[sm * 6 + 5];
        float ctcvr1 = ctr1 * cvr1;
        for (int o = j; o < 10; o += 8) {
            float v;
            switch (o) {
                case 0: v = ctr0; break;
                case 1: v = ctr1; break;
                case 2: v = ctr1; break;
                case 3: v = cvr0; break;
                case 4: v = cvr1; break;
                case 5: v = cvr1; break;
                case 6: v = 1.0f - ctcvr1; break;
                case 7: v = ctcvr1; break;
                case 8: v = ctcvr1; break;
                default: v = imp1; break;
            }
            if (bfe) ((uint16_t*)out)[(size_t)(b0 + sm) * 10 + o] = f2bf(v);
            else     ((float*)out)[(size_t)(b0 + sm) * 10 + o]    = v;
        }
    }
}

// ---------------------------------------------------------------------------
extern "C" void kernel_launch(void* const* d_in, const int* in_sizes, int n_in,
                              void* d_out, int out_size, void* d_ws, size_t ws_size,
                              hipStream_t stream) {
    const void* ids = d_in[0];
    const void* emb = d_in[1];

    char* ws = (char*)d_ws;
    uint16_t* bpk = (uint16_t*)(ws + BP_OFF_B);
    float*    bm  = (float*)(ws + BM_OFF_B);
    uint16_t* btw = (uint16_t*)(ws + BT_OFF_B);
    float*    tb2 = (float*)(ws + TB2_OFF_B);
    float*    owf = (float*)(ws + OWF_OFF_B);
    float*    obf = (float*)(ws + OBF_OFF_B);

    pack_weights<<<49, 256, 0, stream>>>(
        (const uint32_t*)emb,
        d_in[2], d_in[3], d_in[4], d_in[5], d_in[6], d_in[7], d_in[8], d_in[9],
        bpk, bm, btw, tb2, owf, obf);
    moe_fused<<<BATCH / 32, 320, 0, stream>>>(
        ids, emb, bpk, bm, btw, tb2, owf, obf, d_out);
}

// Round 10
// 175.231 us; speedup vs baseline: 1.1345x; 1.1345x over previous
//
#include <hip/hip_runtime.h>
#include <hip/hip_bf16.h>
#include <cstdint>
#include <cstddef>

// Problem constants
#define NFIELD 10
#define BATCH  16384
#define NIDS   20
#define DEMB   16
#define NFEAT  160   // NFIELD * DEMB
#define NEXP   8
#define NS     64
#define NG     3
#define NT     32

// workspace layout (bytes), all regions 16B-aligned
#define BP_OFF_B  0                                // main B-pack: 34*5*64*8*2 = 174,080
#define BM_OFF_B  (BP_OFF_B + 174080)              // main bias fp32[544] = 2,176
#define BT_OFF_B  (BM_OFF_B + 2176)                // tower B-pack: 3*2*2*64*8*2 = 12,288
#define TB2_OFF_B (BT_OFF_B + 12288)               // tower bias fp32[96] = 384
#define OWF_OFF_B (TB2_OFF_B + 384)                // out w fp32[192] = 768
#define OBF_OFF_B (OWF_OFF_B + 768)                // out b fp32[6]

typedef short bfrag __attribute__((ext_vector_type(8)));  // 8 bf16 (4 VGPRs)
typedef float f32x4 __attribute__((ext_vector_type(4)));

__device__ __forceinline__ float bflo(uint32_t u) {
    union { uint32_t u; float f; } c; c.u = u << 16; return c.f;
}
__device__ __forceinline__ float bfhi(uint32_t u) {
    union { uint32_t u; float f; } c; c.u = u & 0xffff0000u; return c.f;
}
__device__ __forceinline__ float bf1(uint16_t v) {
    union { uint32_t u; float f; } c; c.u = ((uint32_t)v) << 16; return c.f;
}
__device__ __forceinline__ uint16_t f2bf(float f) {
    union { float f; uint32_t u; } c; c.f = f;
    uint32_t r = c.u + 0x7fffu + ((c.u >> 16) & 1u);  // RTNE
    return (uint16_t)(r >> 16);
}
__device__ __forceinline__ float ldw(const void* p, int i, bool bf) {
    return bf ? bf1(((const uint16_t*)p)[i]) : ((const float*)p)[i];
}
__device__ __forceinline__ uint16_t ldb16(const void* p, int i, bool bf) {
    return bf ? ((const uint16_t*)p)[i] : f2bf(((const float*)p)[i]);
}
// per-block emb-dtype sniff (thread 0 must call; result via shared)
__device__ __forceinline__ int sniff_bf(const uint32_t* emb_w) {
    int n_bf = 0;
    #pragma unroll
    for (int t = 0; t < 16; ++t) {
        uint32_t wv = emb_w[(size_t)t * 500000];   // <= 30 MB, in-bounds both ways
        uint32_t v = (wv >> 8) & 0x7Fu;
        n_bf += (v >= 0x3Bu && v <= 0x3Fu);
    }
    return n_bf >= 8;
}

// ---------------------------------------------------------------------------
// Kernel P: pack weights (either dtype) into MFMA B-frag bf16 + fp32 biases.
// Main GEMM Wc[k=160][n=544]: n<512 -> expert_w[n>>6][k][n&63];
//   512<=n<536 -> gate_w[(n-512)>>3][k][(n-512)&7]; else 0.
// Frag: [(nt*5+ks)*64+lane]*8+j, element = Wc[ks*32+(lane>>4)*8+j][nt*16+(lane&15)]
// ---------------------------------------------------------------------------
__global__ __launch_bounds__(256) void pack_weights(
    const uint32_t* __restrict__ emb_w,
    const void* __restrict__ ew, const void* __restrict__ eb,
    const void* __restrict__ gw, const void* __restrict__ gb,
    const void* __restrict__ tw, const void* __restrict__ tb,
    const void* __restrict__ ow, const void* __restrict__ ob,
    uint16_t* __restrict__ bp, float* __restrict__ bm,
    uint16_t* __restrict__ bt, float* __restrict__ tb2,
    float* __restrict__ owf, float* __restrict__ obf)
{
    __shared__ int sbf;
    if (threadIdx.x == 0) sbf = sniff_bf(emb_w);
    __syncthreads();
    const bool bf = sbf != 0;

    int i = blockIdx.x * 256 + threadIdx.x;
    if (i < 10880) {                       // main B-pack: 34 tiles * 5 ksteps * 64 lanes
        int nt = i / 320, rem = i % 320;
        int ks = rem / 64, l = rem % 64;
        int n  = nt * 16 + (l & 15);
        int kb = ks * 32 + ((l >> 4) * 8);
        uint16_t v[8];
        #pragma unroll
        for (int j = 0; j < 8; ++j) {
            int k = kb + j;
            uint16_t x;
            if (n < 512)      x = ldb16(ew, (n >> 6) * 10240 + k * 64 + (n & 63), bf);
            else if (n < 536) x = ldb16(gw, ((n - 512) >> 3) * 1280 + k * 8 + ((n - 512) & 7), bf);
            else              x = 0;
            v[j] = x;
        }
        uint4 o;
        o.x = (uint32_t)v[0] | ((uint32_t)v[1] << 16);
        o.y = (uint32_t)v[2] | ((uint32_t)v[3] << 16);
        o.z = (uint32_t)v[4] | ((uint32_t)v[5] << 16);
        o.w = (uint32_t)v[6] | ((uint32_t)v[7] << 16);
        ((uint4*)bp)[i] = o;
    } else if (i < 11648) {                // tower B-pack: 3g * 2nt * 2ks * 64 lanes
        int it = i - 10880;
        int g = it / 256, rem = it % 256;
        int ntile = rem / 128, ks = (rem / 64) & 1, l = rem % 64;
        int t  = ntile * 16 + (l & 15);
        int sb = ks * 32 + ((l >> 4) * 8);
        uint16_t v[8];
        #pragma unroll
        for (int j = 0; j < 8; ++j)
            v[j] = ldb16(tw, g * 2048 + (sb + j) * 32 + t, bf);
        uint4 o;
        o.x = (uint32_t)v[0] | ((uint32_t)v[1] << 16);
        o.y = (uint32_t)v[2] | ((uint32_t)v[3] << 16);
        o.z = (uint32_t)v[4] | ((uint32_t)v[5] << 16);
        o.w = (uint32_t)v[6] | ((uint32_t)v[7] << 16);
        ((uint4*)bt)[it] = o;
    } else if (i < 12192) {                // main bias [544]
        int n = i - 11648;
        bm[n] = (n < 512) ? ldw(eb, n, bf) : (n < 536 ? ldw(gb, n - 512, bf) : 0.0f);
    } else if (i < 12288) {                // tower bias [96]
        int n = i - 12192; tb2[n] = ldw(tb, n, bf);
    } else if (i < 12480) {                // out w [192]
        int n = i - 12288; owf[n] = ldw(ow, n, bf);
    } else if (i < 12486) {                // out b [6]
        int n = i - 12480; obf[n] = ldw(ob, n, bf);
    }
}

// ---------------------------------------------------------------------------
// Kernel F: FUSED gather + MFMA MMoE + towers + ESMM head.
// 32 samples/block, 512 blocks, 320 threads (5 waves).
//   Phase 0: one full-row gather item (f,s) per thread (R8's proven form)
//   GEMM: ALL 5 waves, B-reuse across both M-tiles (7/7/7/7/6 N-tiles/wave;
//         each B-frag loaded once, feeds 2 MFMAs -> B L2 traffic halved)
// LDS overlays: tower over exp; probs over gate. ~50.3 KB -> 3 blocks/CU.
// ---------------------------------------------------------------------------
__global__ __launch_bounds__(320, 3) void moe_fused(
    const void* __restrict__ ids_raw,
    const void* __restrict__ emb_raw,
    const uint16_t* __restrict__ bp,   // main B-pack
    const float*    __restrict__ bm,   // main bias [544] fp32
    const uint16_t* __restrict__ btw,  // tower B-pack
    const float*    __restrict__ btb,  // tower bias [96] fp32
    const float*    __restrict__ owf,  // out w [192] fp32
    const float*    __restrict__ obf,  // out b [6] fp32
    void* __restrict__ out)
{
    __shared__ uint16_t exp_lds[32][520];   // 33,280 B (x-scratch ph0; tower overlay)
    __shared__ float    gate_lds[32][33];   //  4,224 B (prob overlay later)
    __shared__ uint16_t mix_lds[32][200];   // 12,800 B
    __shared__ int      sflags;             // total ~50.3 KB

    float* tow  = (float*)&exp_lds[0][0];   // [32][100] overlay
    float* prob = &gate_lds[0][0];          // [32][6] overlay

    const int tid = threadIdx.x;
    const int w = tid >> 6, l = tid & 63;
    const int lm = l & 15, q = l >> 4;
    const int b0 = blockIdx.x * 32;

    // ---- per-block dtype sniff (thread 0) ----
    if (tid == 0) {
        int n_hi = 0;
        #pragma unroll
        for (int t = 0; t < 16; ++t) {
            size_t p = (size_t)t * 100000;  // pair idx <= 1.5M: in-bounds both ways
            n_hi += (((const uint32_t*)ids_raw)[2 * p + 1] != 0);
        }
        sflags = ((n_hi < 2) ? 1 : 0) | (sniff_bf((const uint32_t*)emb_raw) ? 2 : 0);
    }
    __syncthreads();
    const bool i64 = (sflags & 1) != 0;
    const bool bfe = (sflags & 2) != 0;

    // ---- Phase 0: gather x[32][160] (bf16) into LDS scratch, stride 168 ----
    // 320 items, 320 threads: exactly one per thread; ids read once per item.
    uint16_t* xs = &exp_lds[0][0];
    {
        int f = tid >> 5, s = tid & 31;
        int idv[NIDS];
        if (i64) {
            const int4* p4 = (const int4*)((const long long*)ids_raw +
                                           ((size_t)f * BATCH + (b0 + s)) * NIDS);
            #pragma unroll
            for (int j = 0; j < NIDS / 2; ++j) {
                int4 t4 = p4[j];
                idv[2 * j + 0] = t4.x;
                idv[2 * j + 1] = t4.z;
            }
        } else {
            const int4* p4 = (const int4*)((const int*)ids_raw +
                                           ((size_t)f * BATCH + (b0 + s)) * NIDS);
            #pragma unroll
            for (int j = 0; j < NIDS / 4; ++j) {
                int4 t4 = p4[j];
                idv[4 * j + 0] = t4.x; idv[4 * j + 1] = t4.y;
                idv[4 * j + 2] = t4.z; idv[4 * j + 3] = t4.w;
            }
        }

        float acc[16];
        #pragma unroll
        for (int d = 0; d < 16; ++d) acc[d] = 0.0f;

        if (bfe) {
            #pragma unroll 5
            for (int ll = 0; ll < NIDS; ++ll) {
                const uint4* row = (const uint4*)((const uint16_t*)emb_raw +
                                                  (size_t)idv[ll] * DEMB);
                uint4 r0 = row[0];
                uint4 r1 = row[1];
                acc[0]  += bflo(r0.x); acc[1]  += bfhi(r0.x);
                acc[2]  += bflo(r0.y); acc[3]  += bfhi(r0.y);
                acc[4]  += bflo(r0.z); acc[5]  += bfhi(r0.z);
                acc[6]  += bflo(r0.w); acc[7]  += bfhi(r0.w);
                acc[8]  += bflo(r1.x); acc[9]  += bfhi(r1.x);
                acc[10] += bflo(r1.y); acc[11] += bfhi(r1.y);
                acc[12] += bflo(r1.z); acc[13] += bfhi(r1.z);
                acc[14] += bflo(r1.w); acc[15] += bfhi(r1.w);
            }
        } else {
            #pragma unroll 5
            for (int ll = 0; ll < NIDS; ++ll) {
                const float4* row = (const float4*)((const float*)emb_raw +
                                                    (size_t)idv[ll] * DEMB);
                float4 r0 = row[0], r1 = row[1], r2 = row[2], r3 = row[3];
                acc[0]  += r0.x; acc[1]  += r0.y; acc[2]  += r0.z; acc[3]  += r0.w;
                acc[4]  += r1.x; acc[5]  += r1.y; acc[6]  += r1.z; acc[7]  += r1.w;
                acc[8]  += r2.x; acc[9]  += r2.y; acc[10] += r2.z; acc[11] += r2.w;
                acc[12] += r3.x; acc[13] += r3.y; acc[14] += r3.z; acc[15] += r3.w;
            }
        }

        uint32_t pk[8];
        #pragma unroll
        for (int j = 0; j < 8; ++j)
            pk[j] = (uint32_t)f2bf(acc[2 * j]) | ((uint32_t)f2bf(acc[2 * j + 1]) << 16);
        uint4* dst = (uint4*)(xs + (size_t)s * 168 + f * DEMB);
        dst[0] = make_uint4(pk[0], pk[1], pk[2], pk[3]);
        dst[1] = make_uint4(pk[4], pk[5], pk[6], pk[7]);
    }
    __syncthreads();

    // ---- Phase 1: A fragments for BOTH M-tiles into registers (all waves) ----
    bfrag a0[5], a1[5];
    #pragma unroll
    for (int ks = 0; ks < 5; ++ks) {
        a0[ks] = *(const bfrag*)(xs + (size_t)lm * 168 + ks * 32 + q * 8);
        a1[ks] = *(const bfrag*)(xs + (size_t)(16 + lm) * 168 + ks * 32 + q * 8);
    }
    __syncthreads();   // all reads done before GEMM overwrites the scratch

    // ---- Phase 2: GEMM, all 5 waves, B loaded once per tile (2 MFMAs/frag) ----
    {
        int start = (w < 4) ? w * 7 : 28;
        int cnt   = (w < 4) ? 7 : 6;
        for (int it = 0; it < cnt; ++it) {
            int nt = start + it;
            f32x4 acc0 = {0.0f, 0.0f, 0.0f, 0.0f};
            f32x4 acc1 = {0.0f, 0.0f, 0.0f, 0.0f};
            const bfrag* bpp = (const bfrag*)bp + (size_t)(nt * 5) * 64 + l;
            #pragma unroll
            for (int ks = 0; ks < 5; ++ks) {
                bfrag b = bpp[ks * 64];
                acc0 = __builtin_amdgcn_mfma_f32_16x16x32_bf16(a0[ks], b, acc0, 0, 0, 0);
                acc1 = __builtin_amdgcn_mfma_f32_16x16x32_bf16(a1[ks], b, acc1, 0, 0, 0);
            }
            int col = nt * 16 + lm;
            float bias = bm[col];
            if (col < 512) {
                #pragma unroll
                for (int r = 0; r < 4; ++r) {
                    exp_lds[q * 4 + r][col]      = f2bf(fmaxf(acc0[r] + bias, 0.0f));
                    exp_lds[16 + q * 4 + r][col] = f2bf(fmaxf(acc1[r] + bias, 0.0f));
                }
            } else {
                #pragma unroll
                for (int r = 0; r < 4; ++r) {
                    gate_lds[q * 4 + r][col - 512]      = acc0[r] + bias;
                    gate_lds[16 + q * 4 + r][col - 512] = acc1[r] + bias;
                }
            }
        }
    }
    __syncthreads();

    const int sm = tid >> 3, j = tid & 7;   // 32 samples x 8 threads (tid<256)

    // ---- gate softmax (tid<256, j<3 -> g=j) ----
    if (tid < 256 && j < 3) {
        float* gl = &gate_lds[sm][j * 8];
        float m = gl[0];
        #pragma unroll
        for (int e = 1; e < 8; ++e) m = fmaxf(m, gl[e]);
        float ex[8], s = 0.0f;
        #pragma unroll
        for (int e = 0; e < 8; ++e) { ex[e] = __expf(gl[e] - m); s += ex[e]; }
        float inv = 1.0f / s;
        #pragma unroll
        for (int e = 0; e < 8; ++e) gl[e] = ex[e] * inv;
    }
    __syncthreads();

    // ---- mix[g][s]: tid<256; thread j does s = j*8..j*8+7 for all g ----
    if (tid < 256) {
        for (int g = 0; g < NG; ++g) {
            float m8[8];
            #pragma unroll
            for (int i = 0; i < 8; ++i) m8[i] = 0.0f;
            #pragma unroll
            for (int e = 0; e < NEXP; ++e) {
                float gv = gate_lds[sm][g * 8 + e];
                uint4 u = *(const uint4*)&exp_lds[sm][e * 64 + j * 8];
                m8[0] = fmaf(gv, bflo(u.x), m8[0]); m8[1] = fmaf(gv, bfhi(u.x), m8[1]);
                m8[2] = fmaf(gv, bflo(u.y), m8[2]); m8[3] = fmaf(gv, bfhi(u.y), m8[3]);
                m8[4] = fmaf(gv, bflo(u.z), m8[4]); m8[5] = fmaf(gv, bfhi(u.z), m8[5]);
                m8[6] = fmaf(gv, bflo(u.w), m8[6]); m8[7] = fmaf(gv, bfhi(u.w), m8[7]);
            }
            uint4 o;
            o.x = (uint32_t)f2bf(m8[0]) | ((uint32_t)f2bf(m8[1]) << 16);
            o.y = (uint32_t)f2bf(m8[2]) | ((uint32_t)f2bf(m8[3]) << 16);
            o.z = (uint32_t)f2bf(m8[4]) | ((uint32_t)f2bf(m8[5]) << 16);
            o.w = (uint32_t)f2bf(m8[6]) | ((uint32_t)f2bf(m8[7]) << 16);
            *(uint4*)&mix_lds[sm][g * 64 + j * 8] = o;
        }
    }
    __syncthreads();   // exp region dead; tow overlay live

    // ---- tower MFMA: 12 units (3g x 2mt x 2nt), wave w does u = w, w+5, w+10 ----
    for (int u = w; u < 12; u += 5) {
        int g = u >> 2, mt = (u >> 1) & 1, ntile = u & 1;
        f32x4 acc = {0.0f, 0.0f, 0.0f, 0.0f};
        #pragma unroll
        for (int ks = 0; ks < 2; ++ks) {
            bfrag av = *(const bfrag*)&mix_lds[mt * 16 + lm][g * 64 + ks * 32 + q * 8];
            bfrag bv = *(const bfrag*)(btw + (size_t)((((g * 2 + ntile) * 2 + ks) * 64 + l)) * 8);
            acc = __builtin_amdgcn_mfma_f32_16x16x32_bf16(av, bv, acc, 0, 0, 0);
        }
        int t = ntile * 16 + lm;
        float bias = btb[g * 32 + t];
        #pragma unroll
        for (int r = 0; r < 4; ++r)
            tow[(mt * 16 + q * 4 + r) * 100 + g * 32 + t] = fmaxf(acc[r] + bias, 0.0f);
    }
    __syncthreads();

    // ---- out head: tid<256, j<3 -> g=j: 2 logits, softmax, clip ----
    if (tid < 256 && j < 3) {
        int g = j;
        float l0 = obf[2 * g], l1 = obf[2 * g + 1];
        #pragma unroll 8
        for (int t = 0; t < NT; ++t) {
            float tv = tow[sm * 100 + g * 32 + t];
            l0 = fmaf(tv, owf[g * 64 + 2 * t], l0);
            l1 = fmaf(tv, owf[g * 64 + 2 * t + 1], l1);
        }
        float m  = fmaxf(l0, l1);
        float e0 = __expf(l0 - m);
        float e1 = __expf(l1 - m);
        float inv = 1.0f / (e0 + e1);
        float p0 = fminf(fmaxf(e0 * inv, 1e-15f), 1.0f);
        float p1 = fminf(fmaxf(e1 * inv, 1e-15f), 1.0f);
        prob[sm * 6 + 2 * g + 0] = p0;
        prob[sm * 6 + 2 * g + 1] = p1;
    }
    __syncthreads();

    // ---- assemble 10 outputs per sample (tid<256), dtype per sniff ----
    if (tid < 256) {
        float ctr0 = prob[sm * 6 + 0], ctr1 = prob[sm * 6 + 1];
        float cvr0 = prob[sm * 6 + 2], cvr1 = prob[sm * 6 + 3];
        float imp1 = prob[sm * 6 + 5];
        float ctcvr1 = ctr1 * cvr1;
        for (int o = j; o < 10; o += 8) {
            float v;
            switch (o) {
                case 0: v = ctr0; break;
                case 1: v = ctr1; break;
                case 2: v = ctr1; break;
                case 3: v = cvr0; break;
                case 4: v = cvr1; break;
                case 5: v = cvr1; break;
                case 6: v = 1.0f - ctcvr1; break;
                case 7: v = ctcvr1; break;
                case 8: v = ctcvr1; break;
                default: v = imp1; break;
            }
            if (bfe) ((uint16_t*)out)[(size_t)(b0 + sm) * 10 + o] = f2bf(v);
            else     ((float*)out)[(size_t)(b0 + sm) * 10 + o]    = v;
        }
    }
}

// ---------------------------------------------------------------------------
extern "C" void kernel_launch(void* const* d_in, const int* in_sizes, int n_in,
                              void* d_out, int out_size, void* d_ws, size_t ws_size,
                              hipStream_t stream) {
    const void* ids = d_in[0];
    const void* emb = d_in[1];

    char* ws = (char*)d_ws;
    uint16_t* bpk = (uint16_t*)(ws + BP_OFF_B);
    float*    bm  = (float*)(ws + BM_OFF_B);
    uint16_t* btw = (uint16_t*)(ws + BT_OFF_B);
    float*    tb2 = (float*)(ws + TB2_OFF_B);
    float*    owf = (float*)(ws + OWF_OFF_B);
    float*    obf = (float*)(ws + OBF_OFF_B);

    pack_weights<<<49, 256, 0, stream>>>(
        (const uint32_t*)emb,
        d_in[2], d_in[3], d_in[4], d_in[5], d_in[6], d_in[7], d_in[8], d_in[9],
        bpk, bm, btw, tb2, owf, obf);
    moe_fused<<<BATCH / 32, 320, 0, stream>>>(
        ids, emb, bpk, bm, btw, tb2, owf, obf, d_out);
}